// Round 7
// baseline (521.630 us; speedup 1.0000x reference)
//
#include <hip/hip_runtime.h>

// UpBlock: deconv(8-oct GEMM) -> BN+ELU -> 27-tap gather conv -> BN+ELU
// R6 (resubmit after infra failure): conv gathers int8 rows DIRECTLY into
// VGPRs (4 lanes x 16 B = one 64-B coalesced request per row; A-fragment
// layout == load layout). 2-deep register pipeline, counted vmcnt(8).
// Scales via ds_bpermute. bn_elu_quant restructured to 4 lanes/row.

#define N_PARENT 65536
#define C_IN     128
#define C_OUT    64
#define N_CHILD  (N_PARENT * 8)
#define TAPS     27
#define NBINS    64

typedef __bf16 bf16x8 __attribute__((ext_vector_type(8)));
typedef float  f32x4  __attribute__((ext_vector_type(4)));
typedef int    i32x4  __attribute__((ext_vector_type(4)));

// workspace layout (bytes)
#define Y_OFF     0u          // rows [N_CHILD][128B]: bf16 h, then int8 y8 in first 64B
#define S_OFF     67108864u   // f32 s[N_CHILD] per-row scales = 2097152
#define WTUP_OFF  69206016u   // bf16 WtUp [8][64 n][128 k] = 131072
#define W8CV_OFF  69337088u   // i8 Wt8 [27][64 n][64 j] = 110592
#define TINV_OFF  69447680u   // f32 Tinv[64] = 256
#define S1_OFF    69447936u   // f32 bins1 [64][128] = 32768
#define S2_OFF    69480704u   // f32 bins2 [64][128] = 32768
#define AB1_OFF   69513472u   // f32 a1[64], b1[64] = 512
#define AB2_OFF   69513984u   // f32 a2[64], b2[64] = 512

__device__ __forceinline__ float elu_f(float f) {
    return f > 0.f ? f : (__expf(f) - 1.f);
}

// ---- prep_tc: per-output-column absmax of W_conv -> Tinv[c] = 127/max ----
__global__ __launch_bounds__(256) void prep_tc(const float* __restrict__ wcv,
                                               float* __restrict__ tinv) {
    __shared__ float part[4];
    int c = blockIdx.x, t = threadIdx.x;
    float m = 0.f;
    for (int i = t; i < 1728; i += 256) m = fmaxf(m, fabsf(wcv[i * 64 + c]));
#pragma unroll
    for (int d = 1; d < 64; d <<= 1) m = fmaxf(m, __shfl_xor(m, d));
    if ((t & 63) == 0) part[t >> 6] = m;
    __syncthreads();
    if (t == 0) {
        float mm = fmaxf(fmaxf(part[0], part[1]), fmaxf(part[2], part[3]));
        tinv[c] = 127.f / fmaxf(mm, 1e-20f);
    }
}

// ---- prep: WtUp transpose->bf16; W_conv -> int8 [27][n][j] with Tinv[n] ----
__global__ __launch_bounds__(256) void prep_w(const float* __restrict__ wup,
                                              const float* __restrict__ wcv,
                                              __bf16* __restrict__ wtup,
                                              signed char* __restrict__ w8,
                                              const float* __restrict__ tinv) {
    int i = blockIdx.x * 256 + threadIdx.x;
    if (i < 8 * 64 * 128) {
        int o = i >> 13, rem = i & 8191, n = rem >> 7, k = rem & 127;
        wtup[i] = (__bf16)wup[o * 8192 + k * 64 + n];
    } else {
        int j2 = i - 65536;                   // j2 < 27*64*64 = 110592
        int t = j2 >> 12, rem = j2 & 4095, n = rem >> 6, j = rem & 63;
        float v = wcv[(t * 64 + j) * 64 + n] * tinv[n];
        w8[j2] = (signed char)(int)rintf(v);
    }
}

// ---- kernel A: h[8p+oct] = x[p] @ W_up[oct] (bf16), accumulate BN1 stats ----
__global__ __launch_bounds__(256) void deconv_bn_stats(
    const float* __restrict__ x, const __bf16* __restrict__ wtup,
    __bf16* __restrict__ y, float* __restrict__ bins) {
    __shared__ float ssum[64], ssq[64];
    int tid = threadIdx.x;
    int wave = tid >> 6, lane = tid & 63, lr = lane & 15, lg = lane >> 4;
    int p0 = blockIdx.x * 16;

    if (tid < 64) { ssum[tid] = 0.f; ssq[tid] = 0.f; }

    const float* xrow = x + (size_t)(p0 + lr) * C_IN;
    bf16x8 afr[4];
#pragma unroll
    for (int ks = 0; ks < 4; ++ks) {
        const float* src = xrow + ks * 32 + lg * 8;
        f32x4 u0 = *(const f32x4*)(src);
        f32x4 u1 = *(const f32x4*)(src + 4);
        bf16x8 a;
#pragma unroll
        for (int i = 0; i < 4; ++i) { a[i] = (__bf16)u0[i]; a[4 + i] = (__bf16)u1[i]; }
        afr[ks] = a;
    }

    float lsum[4] = {0.f, 0.f, 0.f, 0.f}, lsq[4] = {0.f, 0.f, 0.f, 0.f};
#pragma unroll
    for (int oo = 0; oo < 2; ++oo) {
        int oct = wave * 2 + oo;
#pragma unroll
        for (int nt = 0; nt < 4; ++nt) {
            f32x4 acc = {0.f, 0.f, 0.f, 0.f};
#pragma unroll
            for (int ks = 0; ks < 4; ++ks) {
                const __bf16* bp = wtup + ((size_t)(oct * 64 + nt * 16 + lr) * C_IN + ks * 32 + lg * 8);
                bf16x8 b = *(const bf16x8*)bp;
                acc = __builtin_amdgcn_mfma_f32_16x16x32_bf16(afr[ks], b, acc, 0, 0, 0);
            }
#pragma unroll
            for (int r = 0; r < 4; ++r) {
                int parent = p0 + lg * 4 + r;
                int child = parent * 8 + oct;
                float v = acc[r];
                y[(size_t)child * 64 + nt * 16 + lr] = (__bf16)v;
                lsum[nt] += v; lsq[nt] += v * v;
            }
        }
    }
    __syncthreads();
#pragma unroll
    for (int nt = 0; nt < 4; ++nt) {
        atomicAdd(&ssum[nt * 16 + lr], lsum[nt]);
        atomicAdd(&ssq[nt * 16 + lr], lsq[nt]);
    }
    __syncthreads();
    if (tid < 64) {
        float* b = bins + (size_t)(blockIdx.x & (NBINS - 1)) * 128;
        atomicAdd(&b[tid], ssum[tid]);
        atomicAdd(&b[64 + tid], ssq[tid]);
    }
}

// ---- finalize: per-channel a = gamma*rstd, b = beta - mu*a ----
__global__ void finalize_stats(const float* __restrict__ bins,
                               const float* __restrict__ gamma,
                               const float* __restrict__ beta,
                               float* __restrict__ ab, float invN) {
    int c = threadIdx.x;  // 64 threads
    float s = 0.f, q = 0.f;
    for (int b = 0; b < NBINS; ++b) { s += bins[b * 128 + c]; q += bins[b * 128 + 64 + c]; }
    float mu = s * invN;
    float var = q * invN - mu * mu;
    float rstd = rsqrtf(var + 1e-5f);
    float a = gamma[c] * rstd;
    ab[c] = a;
    ab[64 + c] = beta[c] - mu * a;
}

// ---- BN1 + ELU + per-row int8 quant, in place (4 lanes per row) ----
__global__ __launch_bounds__(256) void bn_elu_quant(char* __restrict__ ybuf,
                                                    float* __restrict__ sArr,
                                                    const float* __restrict__ ab) {
    int gt = blockIdx.x * 256 + threadIdx.x;
    int row = gt >> 2, q = gt & 3;
    int c0 = q * 16;
    const __bf16* yr = (const __bf16*)(ybuf + (size_t)row * 128) + c0;
    bf16x8 h0 = *(const bf16x8*)(yr);
    bf16x8 h1 = *(const bf16x8*)(yr + 8);
    float v[16];
    float m = 0.f;
#pragma unroll
    for (int j = 0; j < 8; ++j) {
        float f = (float)h0[j] * ab[c0 + j] + ab[64 + c0 + j];
        f = elu_f(f); v[j] = f; m = fmaxf(m, fabsf(f));
    }
#pragma unroll
    for (int j = 0; j < 8; ++j) {
        float f = (float)h1[j] * ab[c0 + 8 + j] + ab[64 + c0 + 8 + j];
        f = elu_f(f); v[8 + j] = f; m = fmaxf(m, fabsf(f));
    }
    // row max across the 4 threads of this row (contiguous lanes)
    m = fmaxf(m, __shfl_xor(m, 1));
    m = fmaxf(m, __shfl_xor(m, 2));
    m = fmaxf(m, 1e-6f);
    float inv = 127.f / m;
    i32x4 pk;
#pragma unroll
    for (int w = 0; w < 4; ++w) {
        int acc = 0;
#pragma unroll
        for (int j = 0; j < 4; ++j) {
            int qv = (int)rintf(v[w * 4 + j] * inv);
            acc |= (qv & 255) << (8 * j);
        }
        pk[w] = acc;
    }
    *(i32x4*)(ybuf + (size_t)row * 128 + q * 16) = pk;
    if (q == 0) sArr[row] = m * (1.f / 127.f);
}

// ---- kernel C: 27-tap gather conv, direct-register gathers ----
// 256 thr = 4 waves; wave owns 32 rows (2 m-tiles) x 64 cols.
// A-fragment == per-lane dwordx4 load: lane(lr,lg) <- y8[idx[lr]][lg*16..+16),
// 4 lg-lanes coalesce to one 64-B request per row. 2-deep pipeline,
// per-stage VMEM queue = 2 A + 2 s + 4 B -> steady wait vmcnt(8).
__global__ __launch_bounds__(256, 4) void conv_bn_stats(
    const char* __restrict__ ybuf, const int* __restrict__ neigh,
    const signed char* __restrict__ w8, const float* __restrict__ sArr,
    float* __restrict__ out, float* __restrict__ bins) {
    __shared__ __align__(16) int idxb_s[4][32 * TAPS];
    __shared__ float ssum[64], ssq[64];
    int tid = threadIdx.x;
    int wave = tid >> 6, lane = tid & 63, lr = lane & 15, lg = lane >> 4;
    int wr0 = blockIdx.x * 128 + wave * 32;

    if (tid < 64) { ssum[tid] = 0.f; ssq[tid] = 0.f; }

    int* idxb = idxb_s[wave];

    // ---- stage this wave's 32x27 neighbor indices into LDS (coalesced) ----
    {
        int base_w = wr0 * TAPS;
#pragma unroll
        for (int j = 0; j < 14; ++j) {
            int w = j * 64 + lane;
            if (w < 32 * TAPS) idxb[w] = neigh[base_w + w];
        }
    }
    asm volatile("s_waitcnt vmcnt(0) lgkmcnt(0)" ::: "memory");
    __builtin_amdgcn_sched_barrier(0);

    f32x4 facc[2][4];
#pragma unroll
    for (int mt = 0; mt < 2; ++mt)
#pragma unroll
        for (int nt = 0; nt < 4; ++nt) facc[mt][nt] = (f32x4){0.f, 0.f, 0.f, 0.f};

    const signed char* w8l = w8 + lr * 64 + lg * 16;   // B-fragment base

    i32x4 abuf[2][2];
    float sbuf[2][2];
    i32x4 bbuf[2][4];
    int icur[2];

    // ---- prologue ----
    {
        int i00 = idxb[lr * TAPS + 0], i01 = idxb[(16 + lr) * TAPS + 0];
        int i10 = idxb[lr * TAPS + 1], i11 = idxb[(16 + lr) * TAPS + 1];
        // stage 0 (8 VMEM)
        abuf[0][0] = *(const i32x4*)(ybuf + (size_t)(unsigned)i00 * 128 + lg * 16);
        abuf[0][1] = *(const i32x4*)(ybuf + (size_t)(unsigned)i01 * 128 + lg * 16);
        sbuf[0][0] = sArr[i00];
        sbuf[0][1] = sArr[i01];
#pragma unroll
        for (int nt = 0; nt < 4; ++nt) bbuf[0][nt] = *(const i32x4*)(w8l + nt * 1024);
        __builtin_amdgcn_sched_barrier(0);
        // stage 1 (8 VMEM)
        abuf[1][0] = *(const i32x4*)(ybuf + (size_t)(unsigned)i10 * 128 + lg * 16);
        abuf[1][1] = *(const i32x4*)(ybuf + (size_t)(unsigned)i11 * 128 + lg * 16);
        sbuf[1][0] = sArr[i10];
        sbuf[1][1] = sArr[i11];
#pragma unroll
        for (int nt = 0; nt < 4; ++nt) bbuf[1][nt] = *(const i32x4*)(w8l + 4096 + nt * 1024);
        __builtin_amdgcn_sched_barrier(0);
        icur[0] = idxb[lr * TAPS + 2];
        icur[1] = idxb[(16 + lr) * TAPS + 2];
    }

#pragma unroll
    for (int k = 0; k < TAPS; ++k) {
        const int p = k & 1;
        // 1. wait: stage k complete, stage k+1 (8 ops) may remain in flight
        if (k < TAPS - 1) { asm volatile("s_waitcnt vmcnt(8)" ::: "memory"); }
        else              { asm volatile("s_waitcnt vmcnt(0)" ::: "memory"); }
        __builtin_amdgcn_sched_barrier(0);
        // 2. redistribute scales: lane needs s of output row lg*4+j (held at lr=lg*4+j)
        int s0i = __float_as_int(sbuf[p][0]);
        int s1i = __float_as_int(sbuf[p][1]);
        f32x4 sv0, sv1;
#pragma unroll
        for (int j = 0; j < 4; ++j) {
            sv0[j] = __int_as_float(__builtin_amdgcn_ds_bpermute((lg * 4 + j) << 2, s0i));
            sv1[j] = __int_as_float(__builtin_amdgcn_ds_bpermute((lg * 4 + j) << 2, s1i));
        }
        asm volatile("s_waitcnt lgkmcnt(0)" ::: "memory");
        __builtin_amdgcn_sched_barrier(0);
        // 3. MFMA + dequant-accumulate
#pragma unroll
        for (int nt = 0; nt < 4; ++nt) {
            i32x4 q0 = __builtin_amdgcn_mfma_i32_16x16x64_i8(abuf[p][0], bbuf[p][nt], (i32x4){0,0,0,0}, 0, 0, 0);
            i32x4 q1 = __builtin_amdgcn_mfma_i32_16x16x64_i8(abuf[p][1], bbuf[p][nt], (i32x4){0,0,0,0}, 0, 0, 0);
#pragma unroll
            for (int j = 0; j < 4; ++j) {
                facc[0][nt][j] += sv0[j] * (float)q0[j];
                facc[1][nt][j] += sv1[j] * (float)q1[j];
            }
        }
        // 4. issue stage k+2 into buffers just consumed (+ read idx for k+3)
        if (k + 2 < TAPS) {
            abuf[p][0] = *(const i32x4*)(ybuf + (size_t)(unsigned)icur[0] * 128 + lg * 16);
            abuf[p][1] = *(const i32x4*)(ybuf + (size_t)(unsigned)icur[1] * 128 + lg * 16);
            sbuf[p][0] = sArr[icur[0]];
            sbuf[p][1] = sArr[icur[1]];
#pragma unroll
            for (int nt = 0; nt < 4; ++nt)
                bbuf[p][nt] = *(const i32x4*)(w8l + (k + 2) * 4096 + nt * 1024);
            if (k + 3 < TAPS) {
                icur[0] = idxb[lr * TAPS + (k + 3)];
                icur[1] = idxb[(16 + lr) * TAPS + (k + 3)];
            }
        }
    }

    float lsum[4] = {0.f, 0.f, 0.f, 0.f}, lsq[4] = {0.f, 0.f, 0.f, 0.f};
#pragma unroll
    for (int mt = 0; mt < 2; ++mt)
#pragma unroll
        for (int nt = 0; nt < 4; ++nt)
#pragma unroll
            for (int r = 0; r < 4; ++r) {
                float v = facc[mt][nt][r];
                int row = wr0 + mt * 16 + lg * 4 + r;
                out[(size_t)row * C_OUT + nt * 16 + lr] = v;
                lsum[nt] += v; lsq[nt] += v * v;
            }
    __syncthreads();
#pragma unroll
    for (int nt = 0; nt < 4; ++nt) {
        atomicAdd(&ssum[nt * 16 + lr], lsum[nt]);
        atomicAdd(&ssq[nt * 16 + lr], lsq[nt]);
    }
    __syncthreads();
    if (tid < 64) {
        float* b = bins + (size_t)(blockIdx.x & (NBINS - 1)) * 128;
        atomicAdd(&b[tid], ssum[tid]);
        atomicAdd(&b[64 + tid], ssq[tid]);
    }
}

// ---- BN2 + ELU applied in place on f32 d_out ----
__global__ __launch_bounds__(256) void bn_elu_out(float* __restrict__ out,
                                                  const float* __restrict__ ab) {
    int tid = blockIdx.x * 256 + threadIdx.x;
    int c0 = (tid * 4) & 63;
    float av[4], bv[4];
#pragma unroll
    for (int j = 0; j < 4; ++j) { av[j] = ab[c0 + j]; bv[j] = ab[64 + c0 + j]; }
#pragma unroll
    for (int t = 0; t < 8; ++t) {
        size_t e = ((size_t)t * 1048576 + tid) * 4;
        f32x4 v = *(const f32x4*)(out + e);
        f32x4 o;
#pragma unroll
        for (int j = 0; j < 4; ++j) o[j] = elu_f(v[j] * av[j] + bv[j]);
        *(f32x4*)(out + e) = o;
    }
}

extern "C" void kernel_launch(void* const* d_in, const int* in_sizes, int n_in,
                              void* d_out, int out_size, void* d_ws, size_t ws_size,
                              hipStream_t stream) {
    const float* x     = (const float*)d_in[0];
    const int*   neigh = (const int*)d_in[1];
    const float* wup   = (const float*)d_in[2];
    const float* wcv   = (const float*)d_in[3];
    const float* g1    = (const float*)d_in[4];
    const float* b1    = (const float*)d_in[5];
    const float* g2    = (const float*)d_in[6];
    const float* b2    = (const float*)d_in[7];
    float* out = (float*)d_out;

    char* ws = (char*)d_ws;
    char*        ybuf  = ws + Y_OFF;
    float*       sArr  = (float*)(ws + S_OFF);
    __bf16*      wtup  = (__bf16*)(ws + WTUP_OFF);
    signed char* w8    = (signed char*)(ws + W8CV_OFF);
    float*       tinv  = (float*)(ws + TINV_OFF);
    float*       bins1 = (float*)(ws + S1_OFF);
    float*       bins2 = (float*)(ws + S2_OFF);
    float*       ab1   = (float*)(ws + AB1_OFF);
    float*       ab2   = (float*)(ws + AB2_OFF);

    hipMemsetAsync(ws + S1_OFF, 0, 32768u * 2 + 1024u, stream);

    prep_tc<<<64, 256, 0, stream>>>(wcv, tinv);
    prep_w<<<688, 256, 0, stream>>>(wup, wcv, wtup, w8, tinv);
    deconv_bn_stats<<<N_PARENT / 16, 256, 0, stream>>>(x, wtup, (__bf16*)ybuf, bins1);
    finalize_stats<<<1, 64, 0, stream>>>(bins1, g1, b1, ab1, 1.f / (float)N_CHILD);
    bn_elu_quant<<<8192, 256, 0, stream>>>(ybuf, sArr, ab1);
    conv_bn_stats<<<N_CHILD / 128, 256, 0, stream>>>(ybuf, neigh, w8, sArr, out, bins2);
    finalize_stats<<<1, 64, 0, stream>>>(bins2, g2, b2, ab2, 1.f / (float)N_CHILD);
    bn_elu_out<<<4096, 256, 0, stream>>>(out, ab2);
}